// Round 1
// baseline (2346.812 us; speedup 1.0000x reference)
//
#include <hip/hip_runtime.h>

#define N_NODES 50000

// ---------------- degree / dis ----------------
__global__ void k_init_deg(float* deg) {
    int i = blockIdx.x * blockDim.x + threadIdx.x;
    if (i < N_NODES) deg[i] = 1.0f;
}

__global__ void k_count(const int* __restrict__ dstArr, int E, float* deg) {
    int e = blockIdx.x * blockDim.x + threadIdx.x;
    if (e < E) atomicAdd(&deg[dstArr[e]], 1.0f);
}

__global__ void k_rsqrt(float* deg) {
    int i = blockIdx.x * blockDim.x + threadIdx.x;
    if (i < N_NODES) deg[i] = rsqrtf(deg[i]);
}

// ---------------- edge-index layout detect + convert ----------------
// If the harness passed int64 (little-endian), all odd 32-bit words of the
// first 2048 words are 0 (values in [0, 50000)). If int32, they are random
// node ids (P(all zero) ~ 0).
__global__ void k_detect(const unsigned* __restrict__ ei, unsigned* flag) {
    __shared__ unsigned nz;
    if (threadIdx.x == 0) nz = 0u;
    __syncthreads();
    unsigned v = 0u;
    for (int i = threadIdx.x; i < 1024; i += 256) v |= ei[2 * i + 1];
    if (v) atomicOr(&nz, 1u);
    __syncthreads();
    if (threadIdx.x == 0) flag[0] = (nz == 0u) ? 1u : 0u;  // 1 => int64 layout
}

__global__ void k_convert(const int* __restrict__ ei, const unsigned* __restrict__ flag,
                          int n, int* __restrict__ sd) {
    int i = blockIdx.x * blockDim.x + threadIdx.x;
    if (i >= n) return;
    sd[i] = flag[0] ? ei[2 * i] : ei[i];
}

// ---------------- GEMM + fused epilogue ----------------
// out rows bm0..bm0+63; thread tile 4 rows x 4 cols.
// h[r][c] = sum_k in[r][k] * W[k][c]   (with optional relu on in)
// agg[r][c] = h[r][c] * dis[r]^2 + b[c]
template <int K, int N, bool RELU>
__global__ __launch_bounds__(512) void k_gemm(const float* __restrict__ in,
                                              const float* __restrict__ W,
                                              const float* __restrict__ bias,
                                              const float* __restrict__ dis,
                                              float* __restrict__ h,
                                              float* __restrict__ agg) {
    const int BM = 64, KB = 32;
    const int T = (N / 4) * 16;  // threads per block
    __shared__ float xt[KB][BM + 4];  // transposed x tile; +4 keeps 16B align
    __shared__ float wl[KB][N];

    const int tx = threadIdx.x;          // 0 .. N/4-1  (col quad)
    const int ty = threadIdx.y;          // 0 .. 15     (row quad)
    const int tid = ty * (N / 4) + tx;
    const int bm0 = blockIdx.x * BM;

    float acc[4][4] = {};

    for (int k0 = 0; k0 < K; k0 += KB) {
        // stage x tile (transposed)
        for (int i = tid; i < BM * (KB / 4); i += T) {
            int row = i / (KB / 4);
            int kq  = i % (KB / 4);
            int r = bm0 + row;
            float4 v = make_float4(0.f, 0.f, 0.f, 0.f);
            if (r < N_NODES) v = *(const float4*)&in[(size_t)r * K + k0 + kq * 4];
            if (RELU) {
                v.x = fmaxf(v.x, 0.f); v.y = fmaxf(v.y, 0.f);
                v.z = fmaxf(v.z, 0.f); v.w = fmaxf(v.w, 0.f);
            }
            xt[kq * 4 + 0][row] = v.x;
            xt[kq * 4 + 1][row] = v.y;
            xt[kq * 4 + 2][row] = v.z;
            xt[kq * 4 + 3][row] = v.w;
        }
        // stage W chunk
        for (int i = tid; i < KB * (N / 4); i += T) {
            int kk = i / (N / 4);
            int cq = i % (N / 4);
            *(float4*)&wl[kk][cq * 4] = *(const float4*)&W[(size_t)(k0 + kk) * N + cq * 4];
        }
        __syncthreads();
        #pragma unroll 4
        for (int kk = 0; kk < KB; ++kk) {
            float4 xv = *(const float4*)&xt[kk][ty * 4];
            float4 wv = *(const float4*)&wl[kk][tx * 4];
            float xr[4] = {xv.x, xv.y, xv.z, xv.w};
            float wr[4] = {wv.x, wv.y, wv.z, wv.w};
            #pragma unroll
            for (int i = 0; i < 4; ++i)
                #pragma unroll
                for (int j = 0; j < 4; ++j)
                    acc[i][j] = fmaf(xr[i], wr[j], acc[i][j]);
        }
        __syncthreads();
    }

    // epilogue
    float4 bv = *(const float4*)&bias[tx * 4];
    #pragma unroll
    for (int i = 0; i < 4; ++i) {
        int r = bm0 + ty * 4 + i;
        if (r >= N_NODES) break;
        float dr = dis[r];
        float d2 = dr * dr;
        float4 hv = make_float4(acc[i][0], acc[i][1], acc[i][2], acc[i][3]);
        *(float4*)&h[(size_t)r * N + tx * 4] = hv;
        float4 av = make_float4(fmaf(hv.x, d2, bv.x), fmaf(hv.y, d2, bv.y),
                                fmaf(hv.z, d2, bv.z), fmaf(hv.w, d2, bv.w));
        *(float4*)&agg[(size_t)r * N + tx * 4] = av;
    }
}

// ---------------- edge aggregation (atomic scatter) ----------------
template <int F>
__global__ __launch_bounds__(256) void k_edge_agg(const int* __restrict__ sd, int E,
                                                  const float* __restrict__ dis,
                                                  const float* __restrict__ h,
                                                  float* __restrict__ agg) {
    const int FQ = F / 4;
    int idx = blockIdx.x * blockDim.x + threadIdx.x;
    if (idx >= E * FQ) return;
    int e = idx / FQ;
    int q = idx % FQ;
    int s = sd[e];
    int d = sd[E + e];
    float coef = dis[s] * dis[d];
    float4 hv = *(const float4*)&h[(size_t)s * F + q * 4];
    float* ap = &agg[(size_t)d * F + q * 4];
    atomicAdd(ap + 0, hv.x * coef);
    atomicAdd(ap + 1, hv.y * coef);
    atomicAdd(ap + 2, hv.z * coef);
    atomicAdd(ap + 3, hv.w * coef);
}

// ---------------- launch ----------------
extern "C" void kernel_launch(void* const* d_in, const int* in_sizes, int n_in,
                              void* d_out, int out_size, void* d_ws, size_t ws_size,
                              hipStream_t stream) {
    const float* x  = (const float*)d_in[0];
    const int*   ei = (const int*)d_in[1];
    const float* W1 = (const float*)d_in[2];
    const float* b1 = (const float*)d_in[3];
    const float* W2 = (const float*)d_in[4];
    const float* b2 = (const float*)d_in[5];
    const float* W3 = (const float*)d_in[6];
    const float* b3 = (const float*)d_in[7];
    float* out = (float*)d_out;

    const int E = in_sizes[1] / 2;

    char* ws = (char*)d_ws;
    size_t off = 0;
    auto alloc = [&](size_t bytes) -> void* {
        void* p = ws + off;
        off += (bytes + 255) & ~(size_t)255;
        return p;
    };
    int*      sd   = (int*)alloc((size_t)2 * E * sizeof(int));
    unsigned* flag = (unsigned*)alloc(256);
    float*    dis  = (float*)alloc((size_t)N_NODES * sizeof(float));
    float*    h    = (float*)alloc((size_t)N_NODES * 128 * sizeof(float));
    float*    agg1 = (float*)alloc((size_t)N_NODES * 128 * sizeof(float));
    float*    agg2 = (float*)alloc((size_t)N_NODES * 64 * sizeof(float));

    // edge index: detect layout, convert to int32 [src | dst]
    k_detect<<<1, 256, 0, stream>>>((const unsigned*)ei, flag);
    k_convert<<<(2 * E + 255) / 256, 256, 0, stream>>>(ei, flag, 2 * E, sd);

    // degrees
    k_init_deg<<<(N_NODES + 255) / 256, 256, 0, stream>>>(dis);
    k_count<<<(E + 255) / 256, 256, 0, stream>>>(sd + E, E, dis);
    k_rsqrt<<<(N_NODES + 255) / 256, 256, 0, stream>>>(dis);

    const int GB = (N_NODES + 63) / 64;  // 782 row-blocks

    // layer 1: [50000,256]@[256,128]
    k_gemm<256, 128, false><<<GB, dim3(32, 16), 0, stream>>>(x, W1, b1, dis, h, agg1);
    {
        int total = E * (128 / 4);
        k_edge_agg<128><<<(total + 255) / 256, 256, 0, stream>>>(sd, E, dis, h, agg1);
    }
    // layer 2: [50000,128]@[128,64], relu on input
    k_gemm<128, 64, true><<<GB, dim3(16, 16), 0, stream>>>(agg1, W2, b2, dis, h, agg2);
    {
        int total = E * (64 / 4);
        k_edge_agg<64><<<(total + 255) / 256, 256, 0, stream>>>(sd, E, dis, h, agg2);
    }
    // layer 3: [50000,64]@[64,16], relu on input, agg -> d_out
    k_gemm<64, 16, true><<<GB, dim3(4, 16), 0, stream>>>(agg2, W3, b3, dis, h, out);
    {
        int total = E * (16 / 4);
        k_edge_agg<16><<<(total + 255) / 256, 256, 0, stream>>>(sd, E, dis, h, out);
    }
}

// Round 2
// 418.176 us; speedup vs baseline: 5.6120x; 5.6120x over previous
//
#include <hip/hip_runtime.h>

#define N_NODES 50000

// ---------------- edge-index layout detect + convert ----------------
__global__ void k_detect(const unsigned* __restrict__ ei, unsigned* flag) {
    __shared__ unsigned nz;
    if (threadIdx.x == 0) nz = 0u;
    __syncthreads();
    unsigned v = 0u;
    for (int i = threadIdx.x; i < 1024; i += 256) v |= ei[2 * i + 1];
    if (v) atomicOr(&nz, 1u);
    __syncthreads();
    if (threadIdx.x == 0) flag[0] = (nz == 0u) ? 1u : 0u;  // 1 => int64 layout
}

__global__ void k_convert(const int* __restrict__ ei, const unsigned* __restrict__ flag,
                          int n, int* __restrict__ sd) {
    int i = blockIdx.x * blockDim.x + threadIdx.x;
    if (i >= n) return;
    sd[i] = flag[0] ? ei[2 * i] : ei[i];
}

// ---------------- degree / dis / CSR ----------------
__global__ void k_zero_int(int* a, int n) {
    int i = blockIdx.x * blockDim.x + threadIdx.x;
    if (i < n) a[i] = 0;
}

__global__ void k_count(const int* __restrict__ dstArr, int E, int* __restrict__ cnt) {
    int e = blockIdx.x * blockDim.x + threadIdx.x;
    if (e < E) atomicAdd(&cnt[dstArr[e]], 1);
}

__global__ void k_dis(const int* __restrict__ cnt, float* __restrict__ dis) {
    int i = blockIdx.x * blockDim.x + threadIdx.x;
    if (i < N_NODES) dis[i] = rsqrtf(1.0f + (float)cnt[i]);
}

// single-block exclusive scan of 50k counts -> rowptr (N+1) and cursor copy
__global__ __launch_bounds__(1024) void k_scan(const int* __restrict__ counts,
                                               int* __restrict__ rowptr,
                                               int* __restrict__ cursor) {
    __shared__ int part[1024];
    const int T = 1024;
    const int per = (N_NODES + T - 1) / T;
    int t = threadIdx.x;
    int beg = t * per;
    int end = min(beg + per, N_NODES);
    int s = 0;
    for (int i = beg; i < end; ++i) s += counts[i];
    part[t] = s;
    __syncthreads();
    for (int ofs = 1; ofs < T; ofs <<= 1) {
        int v = (t >= ofs) ? part[t - ofs] : 0;
        __syncthreads();
        part[t] += v;
        __syncthreads();
    }
    int run = (t == 0) ? 0 : part[t - 1];
    for (int i = beg; i < end; ++i) {
        rowptr[i] = run;
        cursor[i] = run;
        run += counts[i];
    }
    if (t == T - 1) rowptr[N_NODES] = run;
}

// fill CSR records {src, coef} grouped by dst
__global__ void k_fill(const int* __restrict__ sd, int E,
                       const float* __restrict__ dis,
                       int* __restrict__ cursor,
                       float2* __restrict__ recs) {
    int e = blockIdx.x * blockDim.x + threadIdx.x;
    if (e >= E) return;
    int s = sd[e];
    int d = sd[E + e];
    int slot = atomicAdd(&cursor[d], 1);
    float2 r;
    r.x = __int_as_float(s);
    r.y = dis[s] * dis[d];
    recs[slot] = r;
}

// ---------------- GEMM + fused epilogue ----------------
// h[r][c] = sum_k in[r][k] * W[k][c]   (optional relu on in)
// agg[r][c] = h[r][c] * dis[r]^2 + b[c]
template <int K, int N, bool RELU>
__global__ __launch_bounds__(512) void k_gemm(const float* __restrict__ in,
                                              const float* __restrict__ W,
                                              const float* __restrict__ bias,
                                              const float* __restrict__ dis,
                                              float* __restrict__ h,
                                              float* __restrict__ agg) {
    const int BM = 64, KB = 32;
    const int T = (N / 4) * 16;
    __shared__ float xt[KB][BM + 4];
    __shared__ float wl[KB][N];

    const int tx = threadIdx.x;
    const int ty = threadIdx.y;
    const int tid = ty * (N / 4) + tx;
    const int bm0 = blockIdx.x * BM;

    float acc[4][4] = {};

    for (int k0 = 0; k0 < K; k0 += KB) {
        for (int i = tid; i < BM * (KB / 4); i += T) {
            int row = i / (KB / 4);
            int kq  = i % (KB / 4);
            int r = bm0 + row;
            float4 v = make_float4(0.f, 0.f, 0.f, 0.f);
            if (r < N_NODES) v = *(const float4*)&in[(size_t)r * K + k0 + kq * 4];
            if (RELU) {
                v.x = fmaxf(v.x, 0.f); v.y = fmaxf(v.y, 0.f);
                v.z = fmaxf(v.z, 0.f); v.w = fmaxf(v.w, 0.f);
            }
            xt[kq * 4 + 0][row] = v.x;
            xt[kq * 4 + 1][row] = v.y;
            xt[kq * 4 + 2][row] = v.z;
            xt[kq * 4 + 3][row] = v.w;
        }
        for (int i = tid; i < KB * (N / 4); i += T) {
            int kk = i / (N / 4);
            int cq = i % (N / 4);
            *(float4*)&wl[kk][cq * 4] = *(const float4*)&W[(size_t)(k0 + kk) * N + cq * 4];
        }
        __syncthreads();
        #pragma unroll 4
        for (int kk = 0; kk < KB; ++kk) {
            float4 xv = *(const float4*)&xt[kk][ty * 4];
            float4 wv = *(const float4*)&wl[kk][tx * 4];
            float xr[4] = {xv.x, xv.y, xv.z, xv.w};
            float wr[4] = {wv.x, wv.y, wv.z, wv.w};
            #pragma unroll
            for (int i = 0; i < 4; ++i)
                #pragma unroll
                for (int j = 0; j < 4; ++j)
                    acc[i][j] = fmaf(xr[i], wr[j], acc[i][j]);
        }
        __syncthreads();
    }

    float4 bv = *(const float4*)&bias[tx * 4];
    #pragma unroll
    for (int i = 0; i < 4; ++i) {
        int r = bm0 + ty * 4 + i;
        if (r >= N_NODES) break;
        float dr = dis[r];
        float d2 = dr * dr;
        float4 hv = make_float4(acc[i][0], acc[i][1], acc[i][2], acc[i][3]);
        *(float4*)&h[(size_t)r * N + tx * 4] = hv;
        float4 av = make_float4(fmaf(hv.x, d2, bv.x), fmaf(hv.y, d2, bv.y),
                                fmaf(hv.z, d2, bv.z), fmaf(hv.w, d2, bv.w));
        *(float4*)&agg[(size_t)r * N + tx * 4] = av;
    }
}

// ---------------- edge aggregation (CSR gather, no atomics) ----------------
template <int F>
__global__ __launch_bounds__(256) void k_gather(const int* __restrict__ rowptr,
                                                const float2* __restrict__ recs,
                                                const float* __restrict__ h,
                                                float* __restrict__ agg) {
    const int QP = F / 4;  // lanes per dst row
    int tid = blockIdx.x * blockDim.x + threadIdx.x;
    int d = tid / QP;
    int q = tid % QP;
    if (d >= N_NODES) return;
    int beg = rowptr[d];
    int end = rowptr[d + 1];
    float4 acc = make_float4(0.f, 0.f, 0.f, 0.f);
    for (int i = beg; i < end; ++i) {
        float2 r = recs[i];
        int s = __float_as_int(r.x);
        float c = r.y;
        float4 hv = *(const float4*)&h[(size_t)s * F + q * 4];
        acc.x = fmaf(hv.x, c, acc.x);
        acc.y = fmaf(hv.y, c, acc.y);
        acc.z = fmaf(hv.z, c, acc.z);
        acc.w = fmaf(hv.w, c, acc.w);
    }
    float* ap = &agg[(size_t)d * F + q * 4];
    float4 cur = *(const float4*)ap;
    cur.x += acc.x; cur.y += acc.y; cur.z += acc.z; cur.w += acc.w;
    *(float4*)ap = cur;
}

// ---------------- launch ----------------
extern "C" void kernel_launch(void* const* d_in, const int* in_sizes, int n_in,
                              void* d_out, int out_size, void* d_ws, size_t ws_size,
                              hipStream_t stream) {
    const float* x  = (const float*)d_in[0];
    const int*   ei = (const int*)d_in[1];
    const float* W1 = (const float*)d_in[2];
    const float* b1 = (const float*)d_in[3];
    const float* W2 = (const float*)d_in[4];
    const float* b2 = (const float*)d_in[5];
    const float* W3 = (const float*)d_in[6];
    const float* b3 = (const float*)d_in[7];
    float* out = (float*)d_out;

    const int E = in_sizes[1] / 2;

    char* ws = (char*)d_ws;
    size_t off = 0;
    auto alloc = [&](size_t bytes) -> void* {
        void* p = ws + off;
        off += (bytes + 255) & ~(size_t)255;
        return p;
    };
    int*      sd     = (int*)alloc((size_t)2 * E * sizeof(int));
    unsigned* flag   = (unsigned*)alloc(256);
    int*      cnt    = (int*)alloc((size_t)N_NODES * sizeof(int));
    int*      rowptr = (int*)alloc((size_t)(N_NODES + 1) * sizeof(int));
    int*      cursor = (int*)alloc((size_t)N_NODES * sizeof(int));
    float*    dis    = (float*)alloc((size_t)N_NODES * sizeof(float));
    float2*   recs   = (float2*)alloc((size_t)E * sizeof(float2));
    float*    h      = (float*)alloc((size_t)N_NODES * 128 * sizeof(float));
    float*    agg1   = (float*)alloc((size_t)N_NODES * 128 * sizeof(float));
    float*    agg2   = (float*)alloc((size_t)N_NODES * 64 * sizeof(float));

    // edge index -> int32 [src | dst]
    k_detect<<<1, 256, 0, stream>>>((const unsigned*)ei, flag);
    k_convert<<<(2 * E + 255) / 256, 256, 0, stream>>>(ei, flag, 2 * E, sd);

    // degree -> dis, CSR build
    k_zero_int<<<(N_NODES + 255) / 256, 256, 0, stream>>>(cnt, N_NODES);
    k_count<<<(E + 255) / 256, 256, 0, stream>>>(sd + E, E, cnt);
    k_dis<<<(N_NODES + 255) / 256, 256, 0, stream>>>(cnt, dis);
    k_scan<<<1, 1024, 0, stream>>>(cnt, rowptr, cursor);
    k_fill<<<(E + 255) / 256, 256, 0, stream>>>(sd, E, dis, cursor, recs);

    const int GB = (N_NODES + 63) / 64;

    // layer 1: [50000,256]@[256,128]
    k_gemm<256, 128, false><<<GB, dim3(32, 16), 0, stream>>>(x, W1, b1, dis, h, agg1);
    {
        int total = N_NODES * (128 / 4);
        k_gather<128><<<(total + 255) / 256, 256, 0, stream>>>(rowptr, recs, h, agg1);
    }
    // layer 2: [50000,128]@[128,64], relu on input
    k_gemm<128, 64, true><<<GB, dim3(16, 16), 0, stream>>>(agg1, W2, b2, dis, h, agg2);
    {
        int total = N_NODES * (64 / 4);
        k_gather<64><<<(total + 255) / 256, 256, 0, stream>>>(rowptr, recs, h, agg2);
    }
    // layer 3: [50000,64]@[64,16], relu on input, agg -> d_out
    k_gemm<64, 16, true><<<GB, dim3(4, 16), 0, stream>>>(agg2, W3, b3, dis, h, out);
    {
        int total = N_NODES * (16 / 4);
        k_gather<16><<<(total + 255) / 256, 256, 0, stream>>>(rowptr, recs, h, out);
    }
}

// Round 3
// 317.733 us; speedup vs baseline: 7.3861x; 1.3161x over previous
//
#include <hip/hip_runtime.h>

#define N_NODES 50000

// ---------------- edge-index layout detect + convert ----------------
__global__ void k_detect(const unsigned* __restrict__ ei, unsigned* flag) {
    __shared__ unsigned nz;
    if (threadIdx.x == 0) nz = 0u;
    __syncthreads();
    unsigned v = 0u;
    for (int i = threadIdx.x; i < 1024; i += 256) v |= ei[2 * i + 1];
    if (v) atomicOr(&nz, 1u);
    __syncthreads();
    if (threadIdx.x == 0) flag[0] = (nz == 0u) ? 1u : 0u;  // 1 => int64 layout
}

__global__ void k_convert(const int* __restrict__ ei, const unsigned* __restrict__ flag,
                          int n, int* __restrict__ sd) {
    int i = blockIdx.x * blockDim.x + threadIdx.x;
    if (i >= n) return;
    sd[i] = flag[0] ? ei[2 * i] : ei[i];
}

// ---------------- degree / dis / CSR ----------------
__global__ void k_zero_int(int* a, int n) {
    int i = blockIdx.x * blockDim.x + threadIdx.x;
    if (i < n) a[i] = 0;
}

__global__ void k_count(const int* __restrict__ dstArr, int E, int* __restrict__ cnt) {
    int e = blockIdx.x * blockDim.x + threadIdx.x;
    if (e < E) atomicAdd(&cnt[dstArr[e]], 1);
}

__global__ void k_dis(const int* __restrict__ cnt, float* __restrict__ dis) {
    int i = blockIdx.x * blockDim.x + threadIdx.x;
    if (i < N_NODES) dis[i] = rsqrtf(1.0f + (float)cnt[i]);
}

// ---------------- 3-phase parallel exclusive scan ----------------
__global__ __launch_bounds__(256) void k_bsum(const int* __restrict__ counts,
                                              int* __restrict__ bsum) {
    __shared__ int s[256];
    int i = blockIdx.x * 256 + threadIdx.x;
    s[threadIdx.x] = (i < N_NODES) ? counts[i] : 0;
    __syncthreads();
    for (int ofs = 128; ofs > 0; ofs >>= 1) {
        if (threadIdx.x < ofs) s[threadIdx.x] += s[threadIdx.x + ofs];
        __syncthreads();
    }
    if (threadIdx.x == 0) bsum[blockIdx.x] = s[0];
}

__global__ __launch_bounds__(256) void k_bscan(const int* __restrict__ bsum, int nb,
                                               int* __restrict__ boff,
                                               int* __restrict__ rowptrN) {
    __shared__ int s[256];
    int t = threadIdx.x;
    int v = (t < nb) ? bsum[t] : 0;
    s[t] = v;
    __syncthreads();
    for (int ofs = 1; ofs < 256; ofs <<= 1) {
        int u = (t >= ofs) ? s[t - ofs] : 0;
        __syncthreads();
        s[t] += u;
        __syncthreads();
    }
    if (t < nb) boff[t] = s[t] - v;  // exclusive
    if (t == 255) rowptrN[0] = s[255];  // total = E
}

__global__ __launch_bounds__(256) void k_scatter(const int* __restrict__ counts,
                                                 const int* __restrict__ boff,
                                                 int* __restrict__ rowptr,
                                                 int* __restrict__ cursor) {
    __shared__ int s[256];
    int t = threadIdx.x;
    int i = blockIdx.x * 256 + t;
    int v = (i < N_NODES) ? counts[i] : 0;
    s[t] = v;
    __syncthreads();
    for (int ofs = 1; ofs < 256; ofs <<= 1) {
        int u = (t >= ofs) ? s[t - ofs] : 0;
        __syncthreads();
        s[t] += u;
        __syncthreads();
    }
    if (i < N_NODES) {
        int ex = boff[blockIdx.x] + s[t] - v;
        rowptr[i] = ex;
        cursor[i] = ex;
    }
}

// fill CSR records {src, coef} grouped by dst
__global__ void k_fill(const int* __restrict__ sd, int E,
                       const float* __restrict__ dis,
                       int* __restrict__ cursor,
                       float2* __restrict__ recs) {
    int e = blockIdx.x * blockDim.x + threadIdx.x;
    if (e >= E) return;
    int s = sd[e];
    int d = sd[E + e];
    int slot = atomicAdd(&cursor[d], 1);
    float2 r;
    r.x = __int_as_float(s);
    r.y = dis[s] * dis[d];
    recs[slot] = r;
}

// ---------------- GEMM + fused epilogue ----------------
template <int K, int N, bool RELU>
__global__ __launch_bounds__(512) void k_gemm(const float* __restrict__ in,
                                              const float* __restrict__ W,
                                              const float* __restrict__ bias,
                                              const float* __restrict__ dis,
                                              float* __restrict__ h,
                                              float* __restrict__ agg) {
    const int BM = 64, KB = 32;
    const int T = (N / 4) * 16;
    __shared__ float xt[KB][BM + 4];
    __shared__ float wl[KB][N];

    const int tx = threadIdx.x;
    const int ty = threadIdx.y;
    const int tid = ty * (N / 4) + tx;
    const int bm0 = blockIdx.x * BM;

    float acc[4][4] = {};

    for (int k0 = 0; k0 < K; k0 += KB) {
        for (int i = tid; i < BM * (KB / 4); i += T) {
            int row = i / (KB / 4);
            int kq  = i % (KB / 4);
            int r = bm0 + row;
            float4 v = make_float4(0.f, 0.f, 0.f, 0.f);
            if (r < N_NODES) v = *(const float4*)&in[(size_t)r * K + k0 + kq * 4];
            if (RELU) {
                v.x = fmaxf(v.x, 0.f); v.y = fmaxf(v.y, 0.f);
                v.z = fmaxf(v.z, 0.f); v.w = fmaxf(v.w, 0.f);
            }
            xt[kq * 4 + 0][row] = v.x;
            xt[kq * 4 + 1][row] = v.y;
            xt[kq * 4 + 2][row] = v.z;
            xt[kq * 4 + 3][row] = v.w;
        }
        for (int i = tid; i < KB * (N / 4); i += T) {
            int kk = i / (N / 4);
            int cq = i % (N / 4);
            *(float4*)&wl[kk][cq * 4] = *(const float4*)&W[(size_t)(k0 + kk) * N + cq * 4];
        }
        __syncthreads();
        #pragma unroll 4
        for (int kk = 0; kk < KB; ++kk) {
            float4 xv = *(const float4*)&xt[kk][ty * 4];
            float4 wv = *(const float4*)&wl[kk][tx * 4];
            float xr[4] = {xv.x, xv.y, xv.z, xv.w};
            float wr[4] = {wv.x, wv.y, wv.z, wv.w};
            #pragma unroll
            for (int i = 0; i < 4; ++i)
                #pragma unroll
                for (int j = 0; j < 4; ++j)
                    acc[i][j] = fmaf(xr[i], wr[j], acc[i][j]);
        }
        __syncthreads();
    }

    float4 bv = *(const float4*)&bias[tx * 4];
    #pragma unroll
    for (int i = 0; i < 4; ++i) {
        int r = bm0 + ty * 4 + i;
        if (r >= N_NODES) break;
        float dr = dis[r];
        float d2 = dr * dr;
        float4 hv = make_float4(acc[i][0], acc[i][1], acc[i][2], acc[i][3]);
        *(float4*)&h[(size_t)r * N + tx * 4] = hv;
        float4 av = make_float4(fmaf(hv.x, d2, bv.x), fmaf(hv.y, d2, bv.y),
                                fmaf(hv.z, d2, bv.z), fmaf(hv.w, d2, bv.w));
        *(float4*)&agg[(size_t)r * N + tx * 4] = av;
    }
}

// ---------------- edge aggregation (CSR gather, no atomics) ----------------
template <int F>
__global__ __launch_bounds__(256) void k_gather(const int* __restrict__ rowptr,
                                                const float2* __restrict__ recs,
                                                const float* __restrict__ h,
                                                float* __restrict__ agg) {
    const int QP = F / 4;  // lanes per dst row
    int tid = blockIdx.x * blockDim.x + threadIdx.x;
    int d = tid / QP;
    int q = tid % QP;
    if (d >= N_NODES) return;
    int beg = rowptr[d];
    int end = rowptr[d + 1];
    float4 acc = make_float4(0.f, 0.f, 0.f, 0.f);
    for (int i = beg; i < end; ++i) {
        float2 r = recs[i];
        int s = __float_as_int(r.x);
        float c = r.y;
        float4 hv = *(const float4*)&h[(size_t)s * F + q * 4];
        acc.x = fmaf(hv.x, c, acc.x);
        acc.y = fmaf(hv.y, c, acc.y);
        acc.z = fmaf(hv.z, c, acc.z);
        acc.w = fmaf(hv.w, c, acc.w);
    }
    float* ap = &agg[(size_t)d * F + q * 4];
    float4 cur = *(const float4*)ap;
    cur.x += acc.x; cur.y += acc.y; cur.z += acc.z; cur.w += acc.w;
    *(float4*)ap = cur;
}

// ---------------- launch ----------------
extern "C" void kernel_launch(void* const* d_in, const int* in_sizes, int n_in,
                              void* d_out, int out_size, void* d_ws, size_t ws_size,
                              hipStream_t stream) {
    const float* x  = (const float*)d_in[0];
    const int*   ei = (const int*)d_in[1];
    const float* W1 = (const float*)d_in[2];
    const float* b1 = (const float*)d_in[3];
    const float* W2 = (const float*)d_in[4];
    const float* b2 = (const float*)d_in[5];
    const float* W3 = (const float*)d_in[6];
    const float* b3 = (const float*)d_in[7];
    float* out = (float*)d_out;

    const int E = in_sizes[1] / 2;
    const int NB = (N_NODES + 255) / 256;  // scan blocks (196)

    char* ws = (char*)d_ws;
    size_t off = 0;
    auto alloc = [&](size_t bytes) -> void* {
        void* p = ws + off;
        off += (bytes + 255) & ~(size_t)255;
        return p;
    };
    int*      sd     = (int*)alloc((size_t)2 * E * sizeof(int));
    unsigned* flag   = (unsigned*)alloc(256);
    int*      cnt    = (int*)alloc((size_t)N_NODES * sizeof(int));
    int*      rowptr = (int*)alloc((size_t)(N_NODES + 1) * sizeof(int));
    int*      cursor = (int*)alloc((size_t)N_NODES * sizeof(int));
    int*      bsum   = (int*)alloc((size_t)NB * sizeof(int));
    int*      boff   = (int*)alloc((size_t)NB * sizeof(int));
    float*    dis    = (float*)alloc((size_t)N_NODES * sizeof(float));
    float2*   recs   = (float2*)alloc((size_t)E * sizeof(float2));
    float*    h      = (float*)alloc((size_t)N_NODES * 128 * sizeof(float));
    float*    agg1   = (float*)alloc((size_t)N_NODES * 128 * sizeof(float));
    float*    agg2   = (float*)alloc((size_t)N_NODES * 64 * sizeof(float));

    // edge index -> int32 [src | dst]
    k_detect<<<1, 256, 0, stream>>>((const unsigned*)ei, flag);
    k_convert<<<(2 * E + 255) / 256, 256, 0, stream>>>(ei, flag, 2 * E, sd);

    // degree -> dis, CSR build (parallel scan)
    k_zero_int<<<(N_NODES + 255) / 256, 256, 0, stream>>>(cnt, N_NODES);
    k_count<<<(E + 255) / 256, 256, 0, stream>>>(sd + E, E, cnt);
    k_dis<<<(N_NODES + 255) / 256, 256, 0, stream>>>(cnt, dis);
    k_bsum<<<NB, 256, 0, stream>>>(cnt, bsum);
    k_bscan<<<1, 256, 0, stream>>>(bsum, NB, boff, rowptr + N_NODES);
    k_scatter<<<NB, 256, 0, stream>>>(cnt, boff, rowptr, cursor);
    k_fill<<<(E + 255) / 256, 256, 0, stream>>>(sd, E, dis, cursor, recs);

    const int GB = (N_NODES + 63) / 64;

    // layer 1: [50000,256]@[256,128]
    k_gemm<256, 128, false><<<GB, dim3(32, 16), 0, stream>>>(x, W1, b1, dis, h, agg1);
    {
        int total = N_NODES * (128 / 4);
        k_gather<128><<<(total + 255) / 256, 256, 0, stream>>>(rowptr, recs, h, agg1);
    }
    // layer 2: [50000,128]@[128,64], relu on input
    k_gemm<128, 64, true><<<GB, dim3(16, 16), 0, stream>>>(agg1, W2, b2, dis, h, agg2);
    {
        int total = N_NODES * (64 / 4);
        k_gather<64><<<(total + 255) / 256, 256, 0, stream>>>(rowptr, recs, h, agg2);
    }
    // layer 3: [50000,64]@[64,16], relu on input, agg -> d_out
    k_gemm<64, 16, true><<<GB, dim3(4, 16), 0, stream>>>(agg2, W3, b3, dis, h, out);
    {
        int total = N_NODES * (16 / 4);
        k_gather<16><<<(total + 255) / 256, 256, 0, stream>>>(rowptr, recs, h, out);
    }
}

// Round 4
// 286.490 us; speedup vs baseline: 8.1916x; 1.1091x over previous
//
#include <hip/hip_runtime.h>

#define N_NODES 50000

typedef _Float16 h4v __attribute__((ext_vector_type(4)));
typedef _Float16 h8v __attribute__((ext_vector_type(8)));
typedef float    f4v __attribute__((ext_vector_type(4)));

// ---------------- edge-index layout detect + convert ----------------
__global__ void k_detect(const unsigned* __restrict__ ei, unsigned* flag) {
    __shared__ unsigned nz;
    if (threadIdx.x == 0) nz = 0u;
    __syncthreads();
    unsigned v = 0u;
    for (int i = threadIdx.x; i < 1024; i += 256) v |= ei[2 * i + 1];
    if (v) atomicOr(&nz, 1u);
    __syncthreads();
    if (threadIdx.x == 0) flag[0] = (nz == 0u) ? 1u : 0u;  // 1 => int64 layout
}

__global__ void k_convert(const int* __restrict__ ei, const unsigned* __restrict__ flag,
                          int n, int* __restrict__ sd) {
    int i = blockIdx.x * blockDim.x + threadIdx.x;
    if (i >= n) return;
    sd[i] = flag[0] ? ei[2 * i] : ei[i];
}

// ---------------- degree / dis / CSR ----------------
__global__ void k_zero_int(int* a, int n) {
    int i = blockIdx.x * blockDim.x + threadIdx.x;
    if (i < n) a[i] = 0;
}

__global__ void k_count(const int* __restrict__ dstArr, int E, int* __restrict__ cnt) {
    int e = blockIdx.x * blockDim.x + threadIdx.x;
    if (e < E) atomicAdd(&cnt[dstArr[e]], 1);
}

__global__ void k_dis(const int* __restrict__ cnt, float* __restrict__ dis) {
    int i = blockIdx.x * blockDim.x + threadIdx.x;
    if (i < N_NODES) dis[i] = rsqrtf(1.0f + (float)cnt[i]);
}

// ---------------- 3-phase parallel exclusive scan ----------------
__global__ __launch_bounds__(256) void k_bsum(const int* __restrict__ counts,
                                              int* __restrict__ bsum) {
    __shared__ int s[256];
    int i = blockIdx.x * 256 + threadIdx.x;
    s[threadIdx.x] = (i < N_NODES) ? counts[i] : 0;
    __syncthreads();
    for (int ofs = 128; ofs > 0; ofs >>= 1) {
        if (threadIdx.x < ofs) s[threadIdx.x] += s[threadIdx.x + ofs];
        __syncthreads();
    }
    if (threadIdx.x == 0) bsum[blockIdx.x] = s[0];
}

__global__ __launch_bounds__(256) void k_bscan(const int* __restrict__ bsum, int nb,
                                               int* __restrict__ boff,
                                               int* __restrict__ rowptrN) {
    __shared__ int s[256];
    int t = threadIdx.x;
    int v = (t < nb) ? bsum[t] : 0;
    s[t] = v;
    __syncthreads();
    for (int ofs = 1; ofs < 256; ofs <<= 1) {
        int u = (t >= ofs) ? s[t - ofs] : 0;
        __syncthreads();
        s[t] += u;
        __syncthreads();
    }
    if (t < nb) boff[t] = s[t] - v;  // exclusive
    if (t == 255) rowptrN[0] = s[255];  // total = E
}

__global__ __launch_bounds__(256) void k_scatter(const int* __restrict__ counts,
                                                 const int* __restrict__ boff,
                                                 int* __restrict__ rowptr,
                                                 int* __restrict__ cursor) {
    __shared__ int s[256];
    int t = threadIdx.x;
    int i = blockIdx.x * 256 + t;
    int v = (i < N_NODES) ? counts[i] : 0;
    s[t] = v;
    __syncthreads();
    for (int ofs = 1; ofs < 256; ofs <<= 1) {
        int u = (t >= ofs) ? s[t - ofs] : 0;
        __syncthreads();
        s[t] += u;
        __syncthreads();
    }
    if (i < N_NODES) {
        int ex = boff[blockIdx.x] + s[t] - v;
        rowptr[i] = ex;
        cursor[i] = ex;
    }
}

// fill CSR records {src, coef} grouped by dst
__global__ void k_fill(const int* __restrict__ sd, int E,
                       const float* __restrict__ dis,
                       int* __restrict__ cursor,
                       float2* __restrict__ recs) {
    int e = blockIdx.x * blockDim.x + threadIdx.x;
    if (e >= E) return;
    int s = sd[e];
    int d = sd[E + e];
    int slot = atomicAdd(&cursor[d], 1);
    float2 r;
    r.x = __int_as_float(s);
    r.y = dis[s] * dis[d];
    recs[slot] = r;
}

// ---------------- MFMA GEMM (f16 in, f32 acc) + fused epilogue ----------------
// h[r][c] = sum_k in[r][k] * W[k][c]   (optional relu on in)
// agg[r][c] = h[r][c] * dis[r]^2 + b[c]
// Per block: BM=64 rows x N cols. 4 waves; wave w owns rows 16w..16w+15.
template <int K, int N, bool RELU>
__global__ __launch_bounds__(256) void k_gemm_mfma(const float* __restrict__ in,
                                                   const float* __restrict__ W,
                                                   const float* __restrict__ bias,
                                                   const float* __restrict__ dis,
                                                   float* __restrict__ h,
                                                   float* __restrict__ agg) {
    const int BM = 64, BK = 32, PAD = 4;
    const int NF = N / 16;  // 16-col fragments per wave
    __shared__ _Float16 at[BM][BK + PAD];   // [m][k], 72B row stride
    __shared__ _Float16 bt[N][BK + PAD];    // [n][k] (W transposed)

    const int tid  = threadIdx.x;
    const int w    = tid >> 6;
    const int lane = tid & 63;
    const int g    = lane >> 4;   // k-group 0..3
    const int lm   = lane & 15;
    const int bm0  = blockIdx.x * BM;

    f4v acc[NF];
    #pragma unroll
    for (int n = 0; n < NF; ++n) acc[n] = (f4v){0.f, 0.f, 0.f, 0.f};

    for (int k0 = 0; k0 < K; k0 += BK) {
        // stage A tile: 64 x 32 f32 -> f16
        for (int idx = tid; idx < BM * (BK / 4); idx += 256) {
            int row = idx >> 3;       // BK/4 = 8 quads per row
            int q   = idx & 7;
            int r   = bm0 + row;
            float4 v = make_float4(0.f, 0.f, 0.f, 0.f);
            if (r < N_NODES) v = *(const float4*)&in[(size_t)r * K + k0 + q * 4];
            if (RELU) {
                v.x = fmaxf(v.x, 0.f); v.y = fmaxf(v.y, 0.f);
                v.z = fmaxf(v.z, 0.f); v.w = fmaxf(v.w, 0.f);
            }
            h4v hv = {(_Float16)v.x, (_Float16)v.y, (_Float16)v.z, (_Float16)v.w};
            *(h4v*)&at[row][q * 4] = hv;
        }
        // stage B tile transposed: W[k0+kk][n] -> bt[n][kk]
        for (int idx = tid; idx < BK * (N / 4); idx += 256) {
            int kk = idx / (N / 4);
            int nq = idx % (N / 4);
            float4 v = *(const float4*)&W[(size_t)(k0 + kk) * N + nq * 4];
            bt[nq * 4 + 0][kk] = (_Float16)v.x;
            bt[nq * 4 + 1][kk] = (_Float16)v.y;
            bt[nq * 4 + 2][kk] = (_Float16)v.z;
            bt[nq * 4 + 3][kk] = (_Float16)v.w;
        }
        __syncthreads();

        // A fragment: row 16w+lm, k = 4g+[0..3] and 16+4g+[0..3]
        // (any k bijection is valid as long as A and B use the same one)
        int m = 16 * w + lm;
        h4v alo = *(const h4v*)&at[m][g * 4];
        h4v ahi = *(const h4v*)&at[m][16 + g * 4];
        h8v a = {alo[0], alo[1], alo[2], alo[3], ahi[0], ahi[1], ahi[2], ahi[3]};

        #pragma unroll
        for (int n = 0; n < NF; ++n) {
            h4v blo = *(const h4v*)&bt[n * 16 + lm][g * 4];
            h4v bhi = *(const h4v*)&bt[n * 16 + lm][16 + g * 4];
            h8v b = {blo[0], blo[1], blo[2], blo[3], bhi[0], bhi[1], bhi[2], bhi[3]};
            acc[n] = __builtin_amdgcn_mfma_f32_16x16x32_f16(a, b, acc[n], 0, 0, 0);
        }
        __syncthreads();
    }

    // epilogue: D row = bm0 + 16w + 4g + r, col = 16n + lm
    float bv[NF];
    #pragma unroll
    for (int n = 0; n < NF; ++n) bv[n] = bias[n * 16 + lm];
    #pragma unroll
    for (int r = 0; r < 4; ++r) {
        int row = bm0 + 16 * w + 4 * g + r;
        if (row < N_NODES) {
            float dr = dis[row];
            float d2 = dr * dr;
            #pragma unroll
            for (int n = 0; n < NF; ++n) {
                float hv = acc[n][r];
                int col = n * 16 + lm;
                h[(size_t)row * N + col] = hv;
                agg[(size_t)row * N + col] = fmaf(hv, d2, bv[n]);
            }
        }
    }
}

// ---------------- small VALU GEMM (layer 3) ----------------
template <int K, int N, bool RELU>
__global__ __launch_bounds__(512) void k_gemm(const float* __restrict__ in,
                                              const float* __restrict__ W,
                                              const float* __restrict__ bias,
                                              const float* __restrict__ dis,
                                              float* __restrict__ h,
                                              float* __restrict__ agg) {
    const int BM = 64, KB = 32;
    const int T = (N / 4) * 16;
    __shared__ float xt[KB][BM + 4];
    __shared__ float wl[KB][N];

    const int tx = threadIdx.x;
    const int ty = threadIdx.y;
    const int tid = ty * (N / 4) + tx;
    const int bm0 = blockIdx.x * BM;

    float acc[4][4] = {};

    for (int k0 = 0; k0 < K; k0 += KB) {
        for (int i = tid; i < BM * (KB / 4); i += T) {
            int row = i / (KB / 4);
            int kq  = i % (KB / 4);
            int r = bm0 + row;
            float4 v = make_float4(0.f, 0.f, 0.f, 0.f);
            if (r < N_NODES) v = *(const float4*)&in[(size_t)r * K + k0 + kq * 4];
            if (RELU) {
                v.x = fmaxf(v.x, 0.f); v.y = fmaxf(v.y, 0.f);
                v.z = fmaxf(v.z, 0.f); v.w = fmaxf(v.w, 0.f);
            }
            xt[kq * 4 + 0][row] = v.x;
            xt[kq * 4 + 1][row] = v.y;
            xt[kq * 4 + 2][row] = v.z;
            xt[kq * 4 + 3][row] = v.w;
        }
        for (int i = tid; i < KB * (N / 4); i += T) {
            int kk = i / (N / 4);
            int cq = i % (N / 4);
            *(float4*)&wl[kk][cq * 4] = *(const float4*)&W[(size_t)(k0 + kk) * N + cq * 4];
        }
        __syncthreads();
        #pragma unroll 4
        for (int kk = 0; kk < KB; ++kk) {
            float4 xv = *(const float4*)&xt[kk][ty * 4];
            float4 wv = *(const float4*)&wl[kk][tx * 4];
            float xr[4] = {xv.x, xv.y, xv.z, xv.w};
            float wr[4] = {wv.x, wv.y, wv.z, wv.w};
            #pragma unroll
            for (int i = 0; i < 4; ++i)
                #pragma unroll
                for (int j = 0; j < 4; ++j)
                    acc[i][j] = fmaf(xr[i], wr[j], acc[i][j]);
        }
        __syncthreads();
    }

    float4 bv = *(const float4*)&bias[tx * 4];
    #pragma unroll
    for (int i = 0; i < 4; ++i) {
        int r = bm0 + ty * 4 + i;
        if (r >= N_NODES) break;
        float dr = dis[r];
        float d2 = dr * dr;
        float4 hv = make_float4(acc[i][0], acc[i][1], acc[i][2], acc[i][3]);
        *(float4*)&h[(size_t)r * N + tx * 4] = hv;
        float4 av = make_float4(fmaf(hv.x, d2, bv.x), fmaf(hv.y, d2, bv.y),
                                fmaf(hv.z, d2, bv.z), fmaf(hv.w, d2, bv.w));
        *(float4*)&agg[(size_t)r * N + tx * 4] = av;
    }
}

// ---------------- edge aggregation (CSR gather, no atomics) ----------------
template <int F>
__global__ __launch_bounds__(256) void k_gather(const int* __restrict__ rowptr,
                                                const float2* __restrict__ recs,
                                                const float* __restrict__ h,
                                                float* __restrict__ agg) {
    const int QP = F / 4;  // lanes per dst row
    int tid = blockIdx.x * blockDim.x + threadIdx.x;
    int d = tid / QP;
    int q = tid % QP;
    if (d >= N_NODES) return;
    int beg = rowptr[d];
    int end = rowptr[d + 1];
    float4 acc = make_float4(0.f, 0.f, 0.f, 0.f);
    for (int i = beg; i < end; ++i) {
        float2 r = recs[i];
        int s = __float_as_int(r.x);
        float c = r.y;
        float4 hv = *(const float4*)&h[(size_t)s * F + q * 4];
        acc.x = fmaf(hv.x, c, acc.x);
        acc.y = fmaf(hv.y, c, acc.y);
        acc.z = fmaf(hv.z, c, acc.z);
        acc.w = fmaf(hv.w, c, acc.w);
    }
    float* ap = &agg[(size_t)d * F + q * 4];
    float4 cur = *(const float4*)ap;
    cur.x += acc.x; cur.y += acc.y; cur.z += acc.z; cur.w += acc.w;
    *(float4*)ap = cur;
}

// ---------------- launch ----------------
extern "C" void kernel_launch(void* const* d_in, const int* in_sizes, int n_in,
                              void* d_out, int out_size, void* d_ws, size_t ws_size,
                              hipStream_t stream) {
    const float* x  = (const float*)d_in[0];
    const int*   ei = (const int*)d_in[1];
    const float* W1 = (const float*)d_in[2];
    const float* b1 = (const float*)d_in[3];
    const float* W2 = (const float*)d_in[4];
    const float* b2 = (const float*)d_in[5];
    const float* W3 = (const float*)d_in[6];
    const float* b3 = (const float*)d_in[7];
    float* out = (float*)d_out;

    const int E = in_sizes[1] / 2;
    const int NB = (N_NODES + 255) / 256;  // scan blocks (196)

    char* ws = (char*)d_ws;
    size_t off = 0;
    auto alloc = [&](size_t bytes) -> void* {
        void* p = ws + off;
        off += (bytes + 255) & ~(size_t)255;
        return p;
    };
    int*      sd     = (int*)alloc((size_t)2 * E * sizeof(int));
    unsigned* flag   = (unsigned*)alloc(256);
    int*      cnt    = (int*)alloc((size_t)N_NODES * sizeof(int));
    int*      rowptr = (int*)alloc((size_t)(N_NODES + 1) * sizeof(int));
    int*      cursor = (int*)alloc((size_t)N_NODES * sizeof(int));
    int*      bsum   = (int*)alloc((size_t)NB * sizeof(int));
    int*      boff   = (int*)alloc((size_t)NB * sizeof(int));
    float*    dis    = (float*)alloc((size_t)N_NODES * sizeof(float));
    float2*   recs   = (float2*)alloc((size_t)E * sizeof(float2));
    float*    h      = (float*)alloc((size_t)N_NODES * 128 * sizeof(float));
    float*    agg1   = (float*)alloc((size_t)N_NODES * 128 * sizeof(float));
    float*    agg2   = (float*)alloc((size_t)N_NODES * 64 * sizeof(float));

    // edge index -> int32 [src | dst]
    k_detect<<<1, 256, 0, stream>>>((const unsigned*)ei, flag);
    k_convert<<<(2 * E + 255) / 256, 256, 0, stream>>>(ei, flag, 2 * E, sd);

    // degree -> dis, CSR build (parallel scan)
    k_zero_int<<<(N_NODES + 255) / 256, 256, 0, stream>>>(cnt, N_NODES);
    k_count<<<(E + 255) / 256, 256, 0, stream>>>(sd + E, E, cnt);
    k_dis<<<(N_NODES + 255) / 256, 256, 0, stream>>>(cnt, dis);
    k_bsum<<<NB, 256, 0, stream>>>(cnt, bsum);
    k_bscan<<<1, 256, 0, stream>>>(bsum, NB, boff, rowptr + N_NODES);
    k_scatter<<<NB, 256, 0, stream>>>(cnt, boff, rowptr, cursor);
    k_fill<<<(E + 255) / 256, 256, 0, stream>>>(sd, E, dis, cursor, recs);

    const int GB = (N_NODES + 63) / 64;

    // layer 1: [50000,256]@[256,128]  (MFMA f16)
    k_gemm_mfma<256, 128, false><<<GB, 256, 0, stream>>>(x, W1, b1, dis, h, agg1);
    {
        int total = N_NODES * (128 / 4);
        k_gather<128><<<(total + 255) / 256, 256, 0, stream>>>(rowptr, recs, h, agg1);
    }
    // layer 2: [50000,128]@[128,64], relu on input  (MFMA f16)
    k_gemm_mfma<128, 64, true><<<GB, 256, 0, stream>>>(agg1, W2, b2, dis, h, agg2);
    {
        int total = N_NODES * (64 / 4);
        k_gather<64><<<(total + 255) / 256, 256, 0, stream>>>(rowptr, recs, h, agg2);
    }
    // layer 3: [50000,64]@[64,16], relu on input  (VALU)
    k_gemm<64, 16, true><<<GB, dim3(4, 16), 0, stream>>>(agg2, W3, b3, dis, h, out);
    {
        int total = N_NODES * (16 / 4);
        k_gather<16><<<(total + 255) / 256, 256, 0, stream>>>(rowptr, recs, h, out);
    }
}

// Round 5
// 212.367 us; speedup vs baseline: 11.0507x; 1.3490x over previous
//
#include <hip/hip_runtime.h>

#define N_NODES 50000

typedef _Float16 h4v __attribute__((ext_vector_type(4)));
typedef _Float16 h8v __attribute__((ext_vector_type(8)));
typedef float    f4v __attribute__((ext_vector_type(4)));

// ---------------- edge-index layout detect + convert ----------------
__global__ void k_detect(const unsigned* __restrict__ ei, unsigned* flag) {
    __shared__ unsigned nz;
    if (threadIdx.x == 0) nz = 0u;
    __syncthreads();
    unsigned v = 0u;
    for (int i = threadIdx.x; i < 1024; i += 256) v |= ei[2 * i + 1];
    if (v) atomicOr(&nz, 1u);
    __syncthreads();
    if (threadIdx.x == 0) flag[0] = (nz == 0u) ? 1u : 0u;  // 1 => int64 layout
}

__global__ void k_convert(const int* __restrict__ ei, const unsigned* __restrict__ flag,
                          int n, int* __restrict__ sd) {
    int i = blockIdx.x * blockDim.x + threadIdx.x;
    if (i >= n) return;
    sd[i] = flag[0] ? ei[2 * i] : ei[i];
}

// ---------------- degree / dis / CSR ----------------
__global__ void k_zero_int(int* a, int n) {
    int i = blockIdx.x * blockDim.x + threadIdx.x;
    if (i < n) a[i] = 0;
}

__global__ void k_count(const int* __restrict__ dstArr, int E, int* __restrict__ cnt) {
    int e = blockIdx.x * blockDim.x + threadIdx.x;
    if (e < E) atomicAdd(&cnt[dstArr[e]], 1);
}

__global__ void k_dis(const int* __restrict__ cnt, float* __restrict__ dis) {
    int i = blockIdx.x * blockDim.x + threadIdx.x;
    if (i < N_NODES) dis[i] = rsqrtf(1.0f + (float)cnt[i]);
}

// ---------------- 3-phase parallel exclusive scan ----------------
__global__ __launch_bounds__(256) void k_bsum(const int* __restrict__ counts,
                                              int* __restrict__ bsum) {
    __shared__ int s[256];
    int i = blockIdx.x * 256 + threadIdx.x;
    s[threadIdx.x] = (i < N_NODES) ? counts[i] : 0;
    __syncthreads();
    for (int ofs = 128; ofs > 0; ofs >>= 1) {
        if (threadIdx.x < ofs) s[threadIdx.x] += s[threadIdx.x + ofs];
        __syncthreads();
    }
    if (threadIdx.x == 0) bsum[blockIdx.x] = s[0];
}

__global__ __launch_bounds__(256) void k_bscan(const int* __restrict__ bsum, int nb,
                                               int* __restrict__ boff,
                                               int* __restrict__ rowptrN) {
    __shared__ int s[256];
    int t = threadIdx.x;
    int v = (t < nb) ? bsum[t] : 0;
    s[t] = v;
    __syncthreads();
    for (int ofs = 1; ofs < 256; ofs <<= 1) {
        int u = (t >= ofs) ? s[t - ofs] : 0;
        __syncthreads();
        s[t] += u;
        __syncthreads();
    }
    if (t < nb) boff[t] = s[t] - v;  // exclusive
    if (t == 255) rowptrN[0] = s[255];  // total = E
}

__global__ __launch_bounds__(256) void k_scatter(const int* __restrict__ counts,
                                                 const int* __restrict__ boff,
                                                 int* __restrict__ rowptr,
                                                 int* __restrict__ cursor) {
    __shared__ int s[256];
    int t = threadIdx.x;
    int i = blockIdx.x * 256 + t;
    int v = (i < N_NODES) ? counts[i] : 0;
    s[t] = v;
    __syncthreads();
    for (int ofs = 1; ofs < 256; ofs <<= 1) {
        int u = (t >= ofs) ? s[t - ofs] : 0;
        __syncthreads();
        s[t] += u;
        __syncthreads();
    }
    if (i < N_NODES) {
        int ex = boff[blockIdx.x] + s[t] - v;
        rowptr[i] = ex;
        cursor[i] = ex;
    }
}

// fill CSR records {src, coef} grouped by dst
__global__ void k_fill(const int* __restrict__ sd, int E,
                       const float* __restrict__ dis,
                       int* __restrict__ cursor,
                       float2* __restrict__ recs) {
    int e = blockIdx.x * blockDim.x + threadIdx.x;
    if (e >= E) return;
    int s = sd[e];
    int d = sd[E + e];
    int slot = atomicAdd(&cursor[d], 1);
    float2 r;
    r.x = __int_as_float(s);
    r.y = dis[s] * dis[d];
    recs[slot] = r;
}

// ---------------- MFMA GEMM: h16 = f16(relu?(in) @ W) ----------------
// Per block: BM=64 rows x N cols. 4 waves; wave w owns rows 16w..16w+15.
template <int K, int N, bool RELU, typename InT>
__global__ __launch_bounds__(256) void k_gemm_mfma(const InT* __restrict__ in,
                                                   const float* __restrict__ W,
                                                   _Float16* __restrict__ h16) {
    const int BM = 64, BK = 32, PAD = 4;
    const int NF = N / 16;
    __shared__ _Float16 at[BM][BK + PAD];   // [m][k]
    __shared__ _Float16 bt[N][BK + PAD];    // [n][k] (W transposed)

    const int tid  = threadIdx.x;
    const int w    = tid >> 6;
    const int lane = tid & 63;
    const int g    = lane >> 4;   // k-group 0..3
    const int lm   = lane & 15;
    const int bm0  = blockIdx.x * BM;

    f4v acc[NF];
    #pragma unroll
    for (int n = 0; n < NF; ++n) acc[n] = (f4v){0.f, 0.f, 0.f, 0.f};

    for (int k0 = 0; k0 < K; k0 += BK) {
        // stage A tile -> f16
        if constexpr (sizeof(InT) == 4) {
            for (int idx = tid; idx < BM * (BK / 4); idx += 256) {
                int row = idx >> 3;
                int q   = idx & 7;
                int r   = bm0 + row;
                float4 v = make_float4(0.f, 0.f, 0.f, 0.f);
                if (r < N_NODES) v = *(const float4*)&((const float*)in)[(size_t)r * K + k0 + q * 4];
                if (RELU) {
                    v.x = fmaxf(v.x, 0.f); v.y = fmaxf(v.y, 0.f);
                    v.z = fmaxf(v.z, 0.f); v.w = fmaxf(v.w, 0.f);
                }
                h4v hv = {(_Float16)v.x, (_Float16)v.y, (_Float16)v.z, (_Float16)v.w};
                *(h4v*)&at[row][q * 4] = hv;
            }
        } else {
            for (int idx = tid; idx < BM * (BK / 8); idx += 256) {
                int row = idx >> 2;
                int q   = idx & 3;
                int r   = bm0 + row;
                h8v v = {};
                if (r < N_NODES) {
                    v = *(const h8v*)&((const _Float16*)in)[(size_t)r * K + k0 + q * 8];
                    if (RELU) {
                        #pragma unroll
                        for (int j = 0; j < 8; ++j)
                            v[j] = v[j] > (_Float16)0 ? v[j] : (_Float16)0;
                    }
                }
                *(h8v*)&at[row][q * 8] = v;
            }
        }
        // stage B tile transposed: W[k0+kk][n] -> bt[n][kk]
        for (int idx = tid; idx < BK * (N / 4); idx += 256) {
            int kk = idx / (N / 4);
            int nq = idx % (N / 4);
            float4 v = *(const float4*)&W[(size_t)(k0 + kk) * N + nq * 4];
            bt[nq * 4 + 0][kk] = (_Float16)v.x;
            bt[nq * 4 + 1][kk] = (_Float16)v.y;
            bt[nq * 4 + 2][kk] = (_Float16)v.z;
            bt[nq * 4 + 3][kk] = (_Float16)v.w;
        }
        __syncthreads();

        int m = 16 * w + lm;
        h4v alo = *(const h4v*)&at[m][g * 4];
        h4v ahi = *(const h4v*)&at[m][16 + g * 4];
        h8v a = {alo[0], alo[1], alo[2], alo[3], ahi[0], ahi[1], ahi[2], ahi[3]};

        #pragma unroll
        for (int n = 0; n < NF; ++n) {
            h4v blo = *(const h4v*)&bt[n * 16 + lm][g * 4];
            h4v bhi = *(const h4v*)&bt[n * 16 + lm][16 + g * 4];
            h8v b = {blo[0], blo[1], blo[2], blo[3], bhi[0], bhi[1], bhi[2], bhi[3]};
            acc[n] = __builtin_amdgcn_mfma_f32_16x16x32_f16(a, b, acc[n], 0, 0, 0);
        }
        __syncthreads();
    }

    // epilogue: row = bm0 + 16w + 4g + r, col = 16n + lm
    #pragma unroll
    for (int r = 0; r < 4; ++r) {
        int row = bm0 + 16 * w + 4 * g + r;
        if (row < N_NODES) {
            #pragma unroll
            for (int n = 0; n < NF; ++n)
                h16[(size_t)row * N + n * 16 + lm] = (_Float16)acc[n][r];
        }
    }
}

// ---------------- CSR gather (f16 source) + fused self-term + bias ----------------
// agg[d] = sum_edges coef * h16[src] + h16[d]*dis[d]^2 + bias
template <int F, bool FINAL>
__global__ __launch_bounds__(256) void k_gather(const int* __restrict__ rowptr,
                                                const float2* __restrict__ recs,
                                                const _Float16* __restrict__ h16,
                                                const float* __restrict__ dis,
                                                const float* __restrict__ bias,
                                                void* __restrict__ aggv) {
    const int QP = F / 8;  // lanes per dst row, 8 cols per lane
    int tid = blockIdx.x * blockDim.x + threadIdx.x;
    int d = tid / QP;
    int q = tid % QP;
    if (d >= N_NODES) return;
    int beg = rowptr[d];
    int end = rowptr[d + 1];
    float acc[8] = {};
    int i = beg;
    for (; i + 2 <= end; i += 2) {
        float2 r0 = recs[i];
        float2 r1 = recs[i + 1];
        h8v v0 = *(const h8v*)&h16[(size_t)__float_as_int(r0.x) * F + q * 8];
        h8v v1 = *(const h8v*)&h16[(size_t)__float_as_int(r1.x) * F + q * 8];
        #pragma unroll
        for (int j = 0; j < 8; ++j)
            acc[j] = fmaf(r0.y, (float)v0[j], fmaf(r1.y, (float)v1[j], acc[j]));
    }
    if (i < end) {
        float2 r0 = recs[i];
        h8v v0 = *(const h8v*)&h16[(size_t)__float_as_int(r0.x) * F + q * 8];
        #pragma unroll
        for (int j = 0; j < 8; ++j)
            acc[j] = fmaf(r0.y, (float)v0[j], acc[j]);
    }
    // self term + bias
    h8v hd = *(const h8v*)&h16[(size_t)d * F + q * 8];
    float dr = dis[d];
    float d2 = dr * dr;
    #pragma unroll
    for (int j = 0; j < 8; ++j)
        acc[j] = fmaf((float)hd[j], d2, acc[j]) + bias[q * 8 + j];

    if (FINAL) {
        float* out = (float*)aggv + (size_t)d * F + q * 8;
        float4 lo = make_float4(acc[0], acc[1], acc[2], acc[3]);
        float4 hi = make_float4(acc[4], acc[5], acc[6], acc[7]);
        *(float4*)out = lo;
        *(float4*)(out + 4) = hi;
    } else {
        _Float16* a16 = (_Float16*)aggv + (size_t)d * F + q * 8;
        h8v o;
        #pragma unroll
        for (int j = 0; j < 8; ++j) o[j] = (_Float16)acc[j];
        *(h8v*)a16 = o;
    }
}

// ---------------- launch ----------------
extern "C" void kernel_launch(void* const* d_in, const int* in_sizes, int n_in,
                              void* d_out, int out_size, void* d_ws, size_t ws_size,
                              hipStream_t stream) {
    const float* x  = (const float*)d_in[0];
    const int*   ei = (const int*)d_in[1];
    const float* W1 = (const float*)d_in[2];
    const float* b1 = (const float*)d_in[3];
    const float* W2 = (const float*)d_in[4];
    const float* b2 = (const float*)d_in[5];
    const float* W3 = (const float*)d_in[6];
    const float* b3 = (const float*)d_in[7];
    float* out = (float*)d_out;

    const int E = in_sizes[1] / 2;
    const int NB = (N_NODES + 255) / 256;  // scan blocks (196)

    char* ws = (char*)d_ws;
    size_t off = 0;
    auto alloc = [&](size_t bytes) -> void* {
        void* p = ws + off;
        off += (bytes + 255) & ~(size_t)255;
        return p;
    };
    int*       sd     = (int*)alloc((size_t)2 * E * sizeof(int));
    unsigned*  flag   = (unsigned*)alloc(256);
    int*       cnt    = (int*)alloc((size_t)N_NODES * sizeof(int));
    int*       rowptr = (int*)alloc((size_t)(N_NODES + 1) * sizeof(int));
    int*       cursor = (int*)alloc((size_t)N_NODES * sizeof(int));
    int*       bsum   = (int*)alloc((size_t)NB * sizeof(int));
    int*       boff   = (int*)alloc((size_t)NB * sizeof(int));
    float*     dis    = (float*)alloc((size_t)N_NODES * sizeof(float));
    float2*    recs   = (float2*)alloc((size_t)E * sizeof(float2));
    _Float16*  h16    = (_Float16*)alloc((size_t)N_NODES * 128 * sizeof(_Float16));
    _Float16*  agg1   = (_Float16*)alloc((size_t)N_NODES * 128 * sizeof(_Float16));
    _Float16*  agg2   = (_Float16*)alloc((size_t)N_NODES * 64 * sizeof(_Float16));

    // edge index -> int32 [src | dst]
    k_detect<<<1, 256, 0, stream>>>((const unsigned*)ei, flag);
    k_convert<<<(2 * E + 255) / 256, 256, 0, stream>>>(ei, flag, 2 * E, sd);

    // degree -> dis, CSR build (parallel scan)
    k_zero_int<<<(N_NODES + 255) / 256, 256, 0, stream>>>(cnt, N_NODES);
    k_count<<<(E + 255) / 256, 256, 0, stream>>>(sd + E, E, cnt);
    k_dis<<<(N_NODES + 255) / 256, 256, 0, stream>>>(cnt, dis);
    k_bsum<<<NB, 256, 0, stream>>>(cnt, bsum);
    k_bscan<<<1, 256, 0, stream>>>(bsum, NB, boff, rowptr + N_NODES);
    k_scatter<<<NB, 256, 0, stream>>>(cnt, boff, rowptr, cursor);
    k_fill<<<(E + 255) / 256, 256, 0, stream>>>(sd, E, dis, cursor, recs);

    const int GB = (N_NODES + 63) / 64;

    // layer 1: [50000,256]@[256,128]
    k_gemm_mfma<256, 128, false, float><<<GB, 256, 0, stream>>>(x, W1, h16);
    {
        int total = N_NODES * (128 / 8);
        k_gather<128, false><<<(total + 255) / 256, 256, 0, stream>>>(rowptr, recs, h16, dis, b1, agg1);
    }
    // layer 2: [50000,128]@[128,64], relu on input
    k_gemm_mfma<128, 64, true, _Float16><<<GB, 256, 0, stream>>>(agg1, W2, h16);
    {
        int total = N_NODES * (64 / 8);
        k_gather<64, false><<<(total + 255) / 256, 256, 0, stream>>>(rowptr, recs, h16, dis, b2, agg2);
    }
    // layer 3: [50000,64]@[64,16], relu on input -> f32 out
    k_gemm_mfma<64, 16, true, _Float16><<<GB, 256, 0, stream>>>(agg2, W3, h16);
    {
        int total = N_NODES * (16 / 8);
        k_gather<16, true><<<(total + 255) / 256, 256, 0, stream>>>(rowptr, recs, h16, dis, b3, out);
    }
}